// Round 1
// baseline (1097.591 us; speedup 1.0000x reference)
//
#include <hip/hip_runtime.h>
#include <hip/hip_bf16.h>

#define N_NODES  100000
#define N_EDGES  3200000
#define IN_FEAT  512
#define HIDDEN   64
#define N_GRAPHS 2048

// ---------------------------------------------------------------- utilities
__global__ __launch_bounds__(256) void zero_u32(unsigned* __restrict__ p, int n) {
    int i = blockIdx.x * 256 + threadIdx.x;
    if (i < n) p[i] = 0u;
}

__global__ __launch_bounds__(256) void init_deg(int* __restrict__ degi, int n) {
    int i = blockIdx.x * 256 + threadIdx.x;
    if (i < n) degi[i] = 1;              // self-loop contributes 1 to in-degree
}

__global__ __launch_bounds__(256) void deg_count(const int* __restrict__ dst,
                                                 int* __restrict__ degi, int e) {
    int i = blockIdx.x * 256 + threadIdx.x;
    if (i < e) atomicAdd(&degi[dst[i]], 1);
}

__global__ __launch_bounds__(256) void compute_dinv(const int* __restrict__ degi,
                                                    float* __restrict__ dinv, int n) {
    int i = blockIdx.x * 256 + threadIdx.x;
    if (i < n) dinv[i] = 1.0f / sqrtf((float)degi[i]);
}

__global__ __launch_bounds__(256) void count_graphs(const int* __restrict__ batch,
                                                    int* __restrict__ cntg, int n) {
    int i = blockIdx.x * 256 + threadIdx.x;
    if (i < n) atomicAdd(&cntg[batch[i]], 1);
}

// ---------------------------------------------------------------- scan (CSR offsets)
// cnt[n] = degi[n] - 1 (real in-edges, self-loop handled inline in gather)
#define SCAN_CHUNK 2048

__global__ __launch_bounds__(256) void scan_block_sums(const int* __restrict__ degi,
                                                       int* __restrict__ bsums, int n) {
    __shared__ int sdata[256];
    int t = threadIdx.x;
    int base = blockIdx.x * SCAN_CHUNK;
    int s = 0;
    for (int i = 0; i < 8; i++) {
        int idx = base + t * 8 + i;
        if (idx < n) s += degi[idx] - 1;
    }
    sdata[t] = s;
    __syncthreads();
    for (int off = 128; off > 0; off >>= 1) {
        if (t < off) sdata[t] += sdata[t + off];
        __syncthreads();
    }
    if (t == 0) bsums[blockIdx.x] = sdata[0];
}

__global__ void scan_bsums(int* __restrict__ bsums, int nb) {
    if (blockIdx.x == 0 && threadIdx.x == 0) {
        int acc = 0;
        for (int i = 0; i < nb; i++) { int v = bsums[i]; bsums[i] = acc; acc += v; }
    }
}

__global__ __launch_bounds__(256) void scan_write(const int* __restrict__ degi,
                                                  const int* __restrict__ bsums,
                                                  int* __restrict__ row_start,
                                                  int* __restrict__ cur, int n) {
    __shared__ int sthread[256];
    int t = threadIdx.x;
    int base = blockIdx.x * SCAN_CHUNK;
    int local[8];
    int s = 0;
    for (int i = 0; i < 8; i++) {
        int idx = base + t * 8 + i;
        int c = (idx < n) ? (degi[idx] - 1) : 0;
        local[i] = s;
        s += c;
    }
    sthread[t] = s;
    __syncthreads();
    for (int off = 1; off < 256; off <<= 1) {
        int v = (t >= off) ? sthread[t - off] : 0;
        __syncthreads();
        sthread[t] += v;
        __syncthreads();
    }
    int off0 = bsums[blockIdx.x] + sthread[t] - s;   // exclusive prefix for this thread
    for (int i = 0; i < 8; i++) {
        int idx = base + t * 8 + i;
        if (idx < n) {
            int rs = off0 + local[i];
            row_start[idx] = rs;
            cur[idx] = rs;
        }
    }
}

__global__ __launch_bounds__(256) void csr_fill(const int* __restrict__ src,
                                                const int* __restrict__ dst,
                                                const float* __restrict__ dinv,
                                                int* __restrict__ cur,
                                                int* __restrict__ csr_src,
                                                float* __restrict__ csr_w, int e) {
    int i = blockIdx.x * 256 + threadIdx.x;
    if (i >= e) return;
    int d = dst[i];
    int s = src[i];
    int p = atomicAdd(&cur[d], 1);
    csr_src[p] = s;
    csr_w[p] = dinv[s];
}

// ---------------------------------------------------------------- fp32 GEMM: Y[n,64] = X[n,K] @ W[K,64]
template <int K>
__global__ __launch_bounds__(256) void gemm_xw(const float* __restrict__ X,
                                               const float* __restrict__ W,
                                               float* __restrict__ Y, int nrows) {
    constexpr int BM = 128;
    __shared__ float xs[BM][68];   // [row][k] pad 64 -> 68 (keeps 16B align, spreads banks)
    __shared__ float ws[64][64];   // [k][col]
    const int t = threadIdx.x;
    const int row0 = blockIdx.x * BM;
    const int ct = t & 15;         // cols ct*4 .. ct*4+3
    const int rt = t >> 4;         // rows rt + 16*j, j = 0..7
    float acc[8][4] = {};

#pragma unroll 1
    for (int k0 = 0; k0 < K; k0 += 64) {
        // stage W chunk 64x64
#pragma unroll
        for (int p = 0; p < 4; p++) {
            int f = t + p * 256;               // float4 index 0..1023
            int kk = f >> 4, cq = f & 15;
            *(float4*)&ws[kk][cq * 4] =
                *(const float4*)(W + (size_t)(k0 + kk) * 64 + cq * 4);
        }
        // stage X chunk BMx64
#pragma unroll
        for (int p = 0; p < 8; p++) {
            int f = t + p * 256;               // float4 index 0..2047
            int r = f >> 4, kq = f & 15;
            int gr = row0 + r;
            float4 v = make_float4(0.f, 0.f, 0.f, 0.f);
            if (gr < nrows) v = *(const float4*)(X + (size_t)gr * K + k0 + kq * 4);
            *(float4*)&xs[r][kq * 4] = v;
        }
        __syncthreads();

#pragma unroll
        for (int kq = 0; kq < 16; kq++) {
            float4 wv0 = *(float4*)&ws[kq * 4 + 0][ct * 4];
            float4 wv1 = *(float4*)&ws[kq * 4 + 1][ct * 4];
            float4 wv2 = *(float4*)&ws[kq * 4 + 2][ct * 4];
            float4 wv3 = *(float4*)&ws[kq * 4 + 3][ct * 4];
#pragma unroll
            for (int j = 0; j < 8; j++) {
                float4 xv = *(float4*)&xs[rt + 16 * j][kq * 4];
                acc[j][0] = fmaf(xv.x, wv0.x, acc[j][0]);
                acc[j][1] = fmaf(xv.x, wv0.y, acc[j][1]);
                acc[j][2] = fmaf(xv.x, wv0.z, acc[j][2]);
                acc[j][3] = fmaf(xv.x, wv0.w, acc[j][3]);
                acc[j][0] = fmaf(xv.y, wv1.x, acc[j][0]);
                acc[j][1] = fmaf(xv.y, wv1.y, acc[j][1]);
                acc[j][2] = fmaf(xv.y, wv1.z, acc[j][2]);
                acc[j][3] = fmaf(xv.y, wv1.w, acc[j][3]);
                acc[j][0] = fmaf(xv.z, wv2.x, acc[j][0]);
                acc[j][1] = fmaf(xv.z, wv2.y, acc[j][1]);
                acc[j][2] = fmaf(xv.z, wv2.z, acc[j][2]);
                acc[j][3] = fmaf(xv.z, wv2.w, acc[j][3]);
                acc[j][0] = fmaf(xv.w, wv3.x, acc[j][0]);
                acc[j][1] = fmaf(xv.w, wv3.y, acc[j][1]);
                acc[j][2] = fmaf(xv.w, wv3.z, acc[j][2]);
                acc[j][3] = fmaf(xv.w, wv3.w, acc[j][3]);
            }
        }
        __syncthreads();
    }

#pragma unroll
    for (int j = 0; j < 8; j++) {
        int gr = row0 + rt + 16 * j;
        if (gr < nrows)
            *(float4*)(Y + (size_t)gr * 64 + ct * 4) =
                make_float4(acc[j][0], acc[j][1], acc[j][2], acc[j][3]);
    }
}

// ---------------------------------------------------------------- GCN gather (SpMM), wave per node
// out[n,f] = dinv[n] * ( dinv[n]*h[n,f] + sum_src dinv[src]*h[src,f] ) + bias[f]
template <bool RELU, bool POOL>
__global__ __launch_bounds__(256) void gcn_gather(const float* __restrict__ h,
                                                  const float* __restrict__ dinv,
                                                  const int* __restrict__ row_start,
                                                  const int* __restrict__ degi,
                                                  const int* __restrict__ csr_src,
                                                  const float* __restrict__ csr_w,
                                                  const float* __restrict__ bias,
                                                  float* __restrict__ out,
                                                  float* __restrict__ pooled,
                                                  const int* __restrict__ batch, int n) {
    int node = (blockIdx.x * 256 + threadIdx.x) >> 6;
    int lane = threadIdx.x & 63;
    if (node >= n) return;

    int start = row_start[node];
    int de = degi[node] - 1;
    float dn = dinv[node];

    float acc0 = dn * h[(size_t)node * 64 + lane];   // self-loop term
    float acc1 = 0.f, acc2 = 0.f, acc3 = 0.f;

    for (int c = 0; c < de; c += 64) {
        int m = min(64, de - c);
        int sv = 0;
        float wv = 0.f;
        if (lane < m) {
            sv = csr_src[start + c + lane];
            wv = csr_w[start + c + lane];
        }
        int j = 0;
        for (; j + 4 <= m; j += 4) {
            int s0 = __shfl(sv, j + 0);
            int s1 = __shfl(sv, j + 1);
            int s2 = __shfl(sv, j + 2);
            int s3 = __shfl(sv, j + 3);
            float w0 = __shfl(wv, j + 0);
            float w1 = __shfl(wv, j + 1);
            float w2 = __shfl(wv, j + 2);
            float w3 = __shfl(wv, j + 3);
            float v0 = h[(size_t)s0 * 64 + lane];
            float v1 = h[(size_t)s1 * 64 + lane];
            float v2 = h[(size_t)s2 * 64 + lane];
            float v3 = h[(size_t)s3 * 64 + lane];
            acc0 = fmaf(w0, v0, acc0);
            acc1 = fmaf(w1, v1, acc1);
            acc2 = fmaf(w2, v2, acc2);
            acc3 = fmaf(w3, v3, acc3);
        }
        for (; j < m; j++) {
            int s = __shfl(sv, j);
            float w = __shfl(wv, j);
            acc0 = fmaf(w, h[(size_t)s * 64 + lane], acc0);
        }
    }
    float acc = (acc0 + acc1) + (acc2 + acc3);
    float o = fmaf(dn, acc, bias[lane]);
    if (RELU) o = fmaxf(o, 0.f);
    if (POOL) {
        atomicAdd(&pooled[(size_t)batch[node] * 64 + lane], o);
    } else {
        out[(size_t)node * 64 + lane] = o;
    }
}

// ---------------------------------------------------------------- final FC, wave per graph
__global__ __launch_bounds__(256) void final_fc(const float* __restrict__ pooled,
                                                const int* __restrict__ cntg,
                                                const float* __restrict__ fc_w,
                                                const float* __restrict__ fc_b,
                                                float* __restrict__ out, int g) {
    int gid = (blockIdx.x * 256 + threadIdx.x) >> 6;
    int lane = threadIdx.x & 63;
    if (gid >= g) return;
    float c = fmaxf((float)cntg[gid], 1.0f);
    float v = pooled[(size_t)gid * 64 + lane] / c * fc_w[lane];
#pragma unroll
    for (int off = 32; off > 0; off >>= 1) v += __shfl_down(v, off);
    if (lane == 0) out[gid] = v + fc_b[0];
}

// ---------------------------------------------------------------- launch
extern "C" void kernel_launch(void* const* d_in, const int* in_sizes, int n_in,
                              void* d_out, int out_size, void* d_ws, size_t ws_size,
                              hipStream_t stream) {
    const float* x    = (const float*)d_in[0];
    const int*   eidx = (const int*)d_in[1];     // [2, E] flat: src row then dst row
    const int*   batch= (const int*)d_in[2];
    const float* W1   = (const float*)d_in[4];
    const float* b1   = (const float*)d_in[5];
    const float* W2   = (const float*)d_in[6];
    const float* b2   = (const float*)d_in[7];
    const float* fc_w = (const float*)d_in[8];
    const float* fc_b = (const float*)d_in[9];
    float* out = (float*)d_out;

    const int N = in_sizes[0] / IN_FEAT;
    const int E = in_sizes[1] / 2;
    const int G = N_GRAPHS;
    const int* src = eidx;
    const int* dst = eidx + E;

    // workspace carve (all 16B-aligned sizes)
    char* w = (char*)d_ws;
    float* h1   = (float*)w; w += (size_t)N * 64 * 4;   // x @ W1
    float* h1r  = (float*)w; w += (size_t)N * 64 * 4;   // relu(conv1)
    float* h2x  = (float*)w; w += (size_t)N * 64 * 4;   // h1r @ W2
    int*   degi = (int*)w;   w += (size_t)N * 4;
    float* dinv = (float*)w; w += (size_t)N * 4;
    int*   rowst= (int*)w;   w += (size_t)N * 4;
    int*   cur  = (int*)w;   w += (size_t)N * 4;
    int*   bsums= (int*)w;   w += 4096;
    int*   csrs = (int*)w;   w += (size_t)E * 4;
    float* csrw = (float*)w; w += (size_t)E * 4;
    float* pooled = (float*)w; w += (size_t)G * 64 * 4;
    int*   cntg = (int*)w;   w += (size_t)G * 4;

    const int nb_scan = (N + SCAN_CHUNK - 1) / SCAN_CHUNK;

    zero_u32<<<(G * 64 + 255) / 256, 256, 0, stream>>>((unsigned*)pooled, G * 64);
    zero_u32<<<(G + 255) / 256, 256, 0, stream>>>((unsigned*)cntg, G);
    init_deg<<<(N + 255) / 256, 256, 0, stream>>>(degi, N);
    count_graphs<<<(N + 255) / 256, 256, 0, stream>>>(batch, cntg, N);
    deg_count<<<(E + 255) / 256, 256, 0, stream>>>(dst, degi, E);
    compute_dinv<<<(N + 255) / 256, 256, 0, stream>>>(degi, dinv, N);
    scan_block_sums<<<nb_scan, 256, 0, stream>>>(degi, bsums, N);
    scan_bsums<<<1, 64, 0, stream>>>(bsums, nb_scan);
    scan_write<<<nb_scan, 256, 0, stream>>>(degi, bsums, rowst, cur, N);
    csr_fill<<<(E + 255) / 256, 256, 0, stream>>>(src, dst, dinv, cur, csrs, csrw, E);

    gemm_xw<IN_FEAT><<<(N + 127) / 128, 256, 0, stream>>>(x, W1, h1, N);
    gcn_gather<true, false><<<(N * 64 + 255) / 256, 256, 0, stream>>>(
        h1, dinv, rowst, degi, csrs, csrw, b1, h1r, nullptr, batch, N);
    gemm_xw<HIDDEN><<<(N + 127) / 128, 256, 0, stream>>>(h1r, W2, h2x, N);
    gcn_gather<false, true><<<(N * 64 + 255) / 256, 256, 0, stream>>>(
        h2x, dinv, rowst, degi, csrs, csrw, b2, nullptr, pooled, batch, N);
    final_fc<<<(G * 64 + 255) / 256, 256, 0, stream>>>(pooled, cntg, fc_w, fc_b, out, G);
}